// Round 18
// baseline (81.181 us; speedup 1.0000x reference)
//
#include <hip/hip_runtime.h>
#include <hip/hip_bf16.h>
#include <math.h>

#define T_TOK 4096
#define D_MODEL 768
#define H_HEADS 12
#define DH 64
#define SEG 512
#define NSEG 8
#define QKV_LD 2304   // 3*D

typedef __bf16 bf16x8_t __attribute__((ext_vector_type(8)));
typedef float f32x4_t __attribute__((ext_vector_type(4)));
typedef float f32x16_t __attribute__((ext_vector_type(16)));

#define GBK 64
// Q pre-scale: 1/sqrt(64) * log2(e)  (softmax computed in base-2 space)
#define QSCALE 0.18033688011112042f

// compile-time-fenced workgroup barrier (rule #18)
#define FENCED_BARRIER()                         \
    do {                                         \
        __builtin_amdgcn_sched_barrier(0);       \
        __builtin_amdgcn_s_barrier();            \
        __builtin_amdgcn_sched_barrier(0);       \
    } while (0)

// ---------------------------------------------------------------------------
// prep: fp32->bf16 convert of X + transpose-convert of Wqkv, Wo + RoPE table
// ---------------------------------------------------------------------------
__device__ __forceinline__ void tconv_body(const float* __restrict__ in,
                                           __hip_bfloat16* __restrict__ out,
                                           int N, int K, int bx, int by, int tid,
                                           float (*tile)[65]) {
    const int k0 = by * 64;
    const int n0 = bx * 64;
    const int rr = tid >> 4;
    const int cc = (tid & 15) * 4;
#pragma unroll
    for (int i = 0; i < 4; ++i) {
        int r = i * 16 + rr;
        float4 v = *(const float4*)(in + (size_t)(k0 + r) * N + n0 + cc);
        tile[r][cc] = v.x; tile[r][cc + 1] = v.y; tile[r][cc + 2] = v.z; tile[r][cc + 3] = v.w;
    }
    __syncthreads();
#pragma unroll
    for (int i = 0; i < 4; ++i) {
        int n = i * 16 + rr;
        union { __hip_bfloat16 h[4]; ushort4 u; } o;
        o.h[0] = __float2bfloat16(tile[cc + 0][n]);
        o.h[1] = __float2bfloat16(tile[cc + 1][n]);
        o.h[2] = __float2bfloat16(tile[cc + 2][n]);
        o.h[3] = __float2bfloat16(tile[cc + 3][n]);
        *(ushort4*)(out + (size_t)(n0 + n) * K + k0 + cc) = o.u;
    }
}

__global__ __launch_bounds__(256) void prep_inputs(const float* __restrict__ hidden,
                                                   const float* __restrict__ Wqkv,
                                                   const float* __restrict__ Wo,
                                                   const int* __restrict__ pos_ids,
                                                   __hip_bfloat16* __restrict__ Xb,
                                                   __hip_bfloat16* __restrict__ Wqkvt,
                                                   __hip_bfloat16* __restrict__ Wot,
                                                   float2* __restrict__ rtab) {
    __shared__ float tile[64][65];
    const int b = blockIdx.x;
    const int tid = threadIdx.x;
    if (b < 3072) {
        int i = b * 256 + tid;
        float4 v = ((const float4*)hidden)[i];
        union { __hip_bfloat16 h[4]; ushort4 u; } o;
        o.h[0] = __float2bfloat16(v.x); o.h[1] = __float2bfloat16(v.y);
        o.h[2] = __float2bfloat16(v.z); o.h[3] = __float2bfloat16(v.w);
        ((ushort4*)Xb)[i] = o.u;
    } else if (b < 3504) {
        int lb = b - 3072;
        tconv_body(Wqkv, Wqkvt, QKV_LD, D_MODEL, lb % 36, lb / 36, tid, tile);
    } else if (b < 3648) {
        int lb = b - 3504;
        tconv_body(Wo, Wot, D_MODEL, D_MODEL, lb % 12, lb / 12, tid, tile);
    } else {
        int idx = (b - 3648) * 256 + tid;   // T*32 = 131072 exactly
        int t = idx >> 5;
        int i = idx & 31;
        float pos = (float)pos_ids[t];
        float inv_freq = powf(160000.0f, -(float)i / 32.0f);
        float s, c;
        sincosf(pos * inv_freq, &s, &c);
        rtab[idx] = make_float2(c, s);
    }
}

// ---------------------------------------------------------------------------
// QKV GEMM: 256 thr, 4 waves of 32x64, 64x128 tile. A-fragments loaded DIRECT
// from global (L2-hot panel) with 1-step double-register prefetch; only B is
// LDS-staged (gload_lds + counted vmcnt(8)). LDS 32 KB -> 4-5 blocks/CU.
// T1 chunked XCD remap (1152 = 8 x 144); T2 swizzle on B; RoPE-table epilogue.
// ---------------------------------------------------------------------------
__global__ __launch_bounds__(256) void gemm_qkv_fused(const __hip_bfloat16* __restrict__ A,
                                                      const __hip_bfloat16* __restrict__ Bt,
                                                      const float2* __restrict__ rtab,
                                                      __hip_bfloat16* __restrict__ Qb,
                                                      __hip_bfloat16* __restrict__ Kb,
                                                      __hip_bfloat16* __restrict__ Vtb) {
    __shared__ __hip_bfloat16 Bs[2][128 * GBK];   // 32 KB
    const int tid = threadIdx.x;
    const int lane = tid & 63;
    const int wid = tid >> 6;          // 0..3
    const int wr = wid >> 1;           // 0..1
    const int wc = wid & 1;            // 0..1
    const int orig = blockIdx.y * 18 + blockIdx.x;   // 0..1151
    const int wg = (orig & 7) * 144 + (orig >> 3);
    const int m0 = (wg / 18) * 64;
    const int n0 = (wg % 18) * 128;
    const int K = D_MODEL;

    f32x4_t acc[2][4];
#pragma unroll
    for (int i = 0; i < 2; ++i)
#pragma unroll
        for (int j = 0; j < 4; ++j) acc[i][j] = (f32x4_t){0.f, 0.f, 0.f, 0.f};

    const int lr = lane >> 3;
    const int gc = lane & 7;
    const int swzc = (gc ^ lr) << 3;
    const int fr = lane & 15;
    const int l4 = lane >> 4;
    const int fsw = fr & 7;

    // per-lane A row bases (mi = 0/1)
    const __hip_bfloat16* a0 = A + (size_t)(m0 + wr * 32 + fr) * K + l4 * 8;
    const __hip_bfloat16* a1 = a0 + (size_t)16 * K;

#define LOAD_AF(dst_, kt_)                                            \
    do {                                                              \
        dst_[0][0] = *(const bf16x8_t*)(a0 + (kt_) * GBK);            \
        dst_[0][1] = *(const bf16x8_t*)(a0 + (kt_) * GBK + 32);       \
        dst_[1][0] = *(const bf16x8_t*)(a1 + (kt_) * GBK);            \
        dst_[1][1] = *(const bf16x8_t*)(a1 + (kt_) * GBK + 32);       \
    } while (0)

#define STAGE_B(buf_, k0_)                                                            \
    do {                                                                              \
        _Pragma("unroll")                                                             \
        for (int i_ = 0; i_ < 4; ++i_) {                                              \
            const int row_ = wid * 32 + i_ * 8;                                       \
            const __hip_bfloat16* gb_ = Bt + (size_t)(n0 + row_ + lr) * K + (k0_) + swzc; \
            __builtin_amdgcn_global_load_lds(                                         \
                (const __attribute__((address_space(1))) void*)gb_,                   \
                (__attribute__((address_space(3))) void*)(Bs[buf_] + row_ * GBK), 16, 0, 0); \
        }                                                                             \
    } while (0)

#define MFMA_STEP(afx_, cur_)                                                         \
    do {                                                                              \
        _Pragma("unroll")                                                             \
        for (int kk = 0; kk < 2; ++kk) {                                              \
            const int rg = ((kk * 4 + l4) ^ fsw) << 3;                                \
            bf16x8_t bfr[4];                                                          \
            _Pragma("unroll")                                                         \
            for (int ni = 0; ni < 4; ++ni)                                            \
                bfr[ni] = *(const bf16x8_t*)(Bs[cur_] + (wc * 64 + ni * 16 + fr) * GBK + rg); \
            _Pragma("unroll")                                                         \
            for (int mi = 0; mi < 2; ++mi)                                            \
                _Pragma("unroll")                                                     \
                for (int ni = 0; ni < 4; ++ni)                                        \
                    acc[mi][ni] = __builtin_amdgcn_mfma_f32_16x16x32_bf16(            \
                        afx_[mi][kk], bfr[ni], acc[mi][ni], 0, 0, 0);                 \
        }                                                                             \
    } while (0)

    bf16x8_t afA[2][2], afB[2][2];
    LOAD_AF(afA, 0);
    STAGE_B(0, 0);
#pragma unroll
    for (int kt = 0; kt < 12; ++kt) {
        if ((kt & 1) == 0) {
            if (kt < 11) {
                LOAD_AF(afB, kt + 1);
                STAGE_B((kt + 1) & 1, (kt + 1) * GBK);
                asm volatile("s_waitcnt vmcnt(8)" ::: "memory");
            } else {
                asm volatile("s_waitcnt vmcnt(0)" ::: "memory");
            }
            FENCED_BARRIER();
            MFMA_STEP(afA, kt & 1);
        } else {
            if (kt < 11) {
                LOAD_AF(afA, kt + 1);
                STAGE_B((kt + 1) & 1, (kt + 1) * GBK);
                asm volatile("s_waitcnt vmcnt(8)" ::: "memory");
            } else {
                asm volatile("s_waitcnt vmcnt(0)" ::: "memory");
            }
            FENCED_BARRIER();
            MFMA_STEP(afB, kt & 1);
        }
        asm volatile("" ::: "memory");
        FENCED_BARRIER();
    }
#undef LOAD_AF
#undef STAGE_B
#undef MFMA_STEP

    // ---- fused epilogue (identical to round 16/17) ----
    const int colbase = n0 + wc * 64;
    const int chunk = colbase >> 6;          // 0..35
    const int part = chunk / H_HEADS;        // 0=q 1=k 2=v
    const int h = chunk % H_HEADS;
    const int trow0 = m0 + wr * 32;

    if (part == 2) {
        const int seg = trow0 >> 9;
        const int key0 = (trow0 & 511) + l4 * 4;
        __hip_bfloat16* vdst = Vtb + ((size_t)(h * NSEG + seg) * DH) * SEG;
#pragma unroll
        for (int mi = 0; mi < 2; ++mi)
#pragma unroll
            for (int ni = 0; ni < 4; ++ni) {
                int d = ni * 16 + fr;
                union { __hip_bfloat16 h2[4]; ushort4 u; } o;
#pragma unroll
                for (int j = 0; j < 4; ++j) o.h2[j] = __float2bfloat16(acc[mi][ni][j]);
                *(ushort4*)(vdst + (size_t)d * SEG + key0 + mi * 16) = o.u;
            }
    } else {
        __hip_bfloat16* dst = (part == 0) ? Qb : Kb;
        const float scale = (part == 0) ? QSCALE : 1.0f;
#pragma unroll
        for (int mi = 0; mi < 2; ++mi)
#pragma unroll
            for (int j = 0; j < 4; ++j) {
                int t = trow0 + mi * 16 + l4 * 4 + j;
                const float2* tb = rtab + (size_t)t * 32;
                float2 cs0 = tb[fr];
                float2 cs1 = tb[16 + fr];
                __hip_bfloat16* op = dst + ((size_t)h * T_TOK + t) * DH;
                float x1, x2;
                x1 = acc[mi][0][j]; x2 = acc[mi][2][j];
                op[fr]      = __float2bfloat16((x1 * cs0.x - x2 * cs0.y) * scale);
                op[fr + 32] = __float2bfloat16((x2 * cs0.x + x1 * cs0.y) * scale);
                x1 = acc[mi][1][j]; x2 = acc[mi][3][j];
                op[16 + fr] = __float2bfloat16((x1 * cs1.x - x2 * cs1.y) * scale);
                op[48 + fr] = __float2bfloat16((x2 * cs1.x + x1 * cs1.y) * scale);
            }
    }
}

// ---------------------------------------------------------------------------
// Wo GEMM: 64x64 tile, 256 thr, 768 blocks; T2 swizzle + T1 XCD remap
// ---------------------------------------------------------------------------
__global__ __launch_bounds__(256) void gemm_wo64(const __hip_bfloat16* __restrict__ A,
                                                 const __hip_bfloat16* __restrict__ Bt,
                                                 float* __restrict__ C) {
    __shared__ __hip_bfloat16 As[2][64 * GBK];
    __shared__ __hip_bfloat16 Bs[2][64 * GBK];
    const int tid = threadIdx.x;
    const int lane = tid & 63;
    const int wid = tid >> 6;
    const int wr = wid >> 1, wc = wid & 1;
    const int orig = blockIdx.y * 12 + blockIdx.x;   // 0..767
    const int wg = (orig & 7) * 96 + (orig >> 3);
    const int m0 = (wg / 12) * 64;
    const int n0 = (wg % 12) * 64;
    const int K = D_MODEL;
    const int N = D_MODEL;

    f32x4_t acc[2][2];
#pragma unroll
    for (int i = 0; i < 2; ++i)
#pragma unroll
        for (int j = 0; j < 2; ++j) acc[i][j] = (f32x4_t){0.f, 0.f, 0.f, 0.f};

    const int lr = lane >> 3;
    const int gc = lane & 7;
    const int swzc = (gc ^ lr) << 3;
    const int fr = lane & 15;
    const int l4 = lane >> 4;
    const int fsw = fr & 7;

#define STAGE_W(buf_, k0_)                                                            \
    do {                                                                              \
        _Pragma("unroll")                                                             \
        for (int i_ = 0; i_ < 2; ++i_) {                                              \
            const int row_ = i_ * 32 + wid * 8;                                       \
            const __hip_bfloat16* ga_ = A + (size_t)(m0 + row_ + lr) * K + (k0_) + swzc; \
            __builtin_amdgcn_global_load_lds(                                         \
                (const __attribute__((address_space(1))) void*)ga_,                   \
                (__attribute__((address_space(3))) void*)(As[buf_] + row_ * GBK), 16, 0, 0); \
            const __hip_bfloat16* gb_ = Bt + (size_t)(n0 + row_ + lr) * K + (k0_) + swzc; \
            __builtin_amdgcn_global_load_lds(                                         \
                (const __attribute__((address_space(1))) void*)gb_,                   \
                (__attribute__((address_space(3))) void*)(Bs[buf_] + row_ * GBK), 16, 0, 0); \
        }                                                                             \
    } while (0)

    const int NKT = K / GBK;   // 12
    STAGE_W(0, 0);
    for (int kt = 0; kt < NKT; ++kt) {
        const int cur = kt & 1;
        if (kt < NKT - 1) {
            STAGE_W(cur ^ 1, (kt + 1) * GBK);
            asm volatile("s_waitcnt vmcnt(4)" ::: "memory");
        } else {
            asm volatile("s_waitcnt vmcnt(0)" ::: "memory");
        }
        FENCED_BARRIER();
#pragma unroll
        for (int kk = 0; kk < 2; ++kk) {
            const int rg = ((kk * 4 + l4) ^ fsw) << 3;
            bf16x8_t af[2], bfr[2];
#pragma unroll
            for (int mi = 0; mi < 2; ++mi)
                af[mi] = *(const bf16x8_t*)(As[cur] + (wr * 32 + mi * 16 + fr) * GBK + rg);
#pragma unroll
            for (int ni = 0; ni < 2; ++ni)
                bfr[ni] = *(const bf16x8_t*)(Bs[cur] + (wc * 32 + ni * 16 + fr) * GBK + rg);
#pragma unroll
            for (int mi = 0; mi < 2; ++mi)
#pragma unroll
                for (int ni = 0; ni < 2; ++ni)
                    acc[mi][ni] = __builtin_amdgcn_mfma_f32_16x16x32_bf16(
                        af[mi], bfr[ni], acc[mi][ni], 0, 0, 0);
        }
        asm volatile("" ::: "memory");
        FENCED_BARRIER();
    }
#undef STAGE_W

    float* Cb = C + (size_t)(m0 + wr * 32) * N + n0 + wc * 32;
#pragma unroll
    for (int mi = 0; mi < 2; ++mi)
#pragma unroll
        for (int ni = 0; ni < 2; ++ni)
#pragma unroll
            for (int j = 0; j < 4; ++j) {
                int r = mi * 16 + (lane >> 4) * 4 + j;
                Cb[(size_t)r * N + ni * 16 + fr] = acc[mi][ni][j];
            }
}

// ---------------- parity-split swapped-QK flash attention -------------------
__device__ __forceinline__ unsigned pk2(float a, float b) {
    unsigned ua = (unsigned)__bfloat16_as_ushort(__float2bfloat16(a));
    unsigned ub = (unsigned)__bfloat16_as_ushort(__float2bfloat16(b));
    return ua | (ub << 16);
}

__global__ __launch_bounds__(256) void attn_mfma(const __hip_bfloat16* __restrict__ Qb,
                                                 const __hip_bfloat16* __restrict__ Kb,
                                                 const __hip_bfloat16* __restrict__ Vtb,
                                                 __hip_bfloat16* __restrict__ attnb) {
    __shared__ __hip_bfloat16 KS[2][64 * 64];   // [parity]
    __shared__ __hip_bfloat16 VS[2][64 * 64];

    const int tid = threadIdx.x;
    const int lane = tid & 63;
    const int w = tid >> 6;        // 0..3
    const int qw = w & 1;          // q-row half
    const int par = w >> 1;        // kv parity
    const int hi = lane >> 5;
    const int l31 = lane & 31;
    const int orig = blockIdx.x;                 // 0..767
    const int wg = (orig & 7) * 96 + (orig >> 3);
    const int qt = wg & 7;
    const int hs = wg >> 3;
    const int h = hs % H_HEADS;
    const int seg = hs / H_HEADS;
    const int t0 = seg * SEG + qt * 64 + qw * 32;

    const __hip_bfloat16* kb = Kb + ((size_t)h * T_TOK + seg * SEG) * DH;
    const __hip_bfloat16* vb = Vtb + (size_t)(h * NSEG + seg) * DH * SEG;

    bf16x8_t qf[4];
    {
        const __hip_bfloat16* qp = Qb + ((size_t)h * T_TOK + t0 + l31) * DH + hi * 8;
#pragma unroll
        for (int s = 0; s < 4; ++s) qf[s] = *(const bf16x8_t*)(qp + s * 16);
    }

    const int gr = lane >> 3;
    const int gc = lane & 7;

    f32x16_t ot[2];
#pragma unroll
    for (int n = 0; n < 2; ++n)
#pragma unroll
        for (int r = 0; r < 16; ++r) ot[n][r] = 0.f;
    float lrun = 0.f;

    for (int it = 0; it < 4; ++it) {
        const int tile = 2 * it + par;
#pragma unroll
        for (int i = 0; i < 4; ++i) {
            int G = i * 128 + qw * 64;
            int rk = (G >> 3) + gr;
            const __hip_bfloat16* sk = kb + (size_t)(tile * 64 + rk) * DH + ((gc ^ (rk & 7)) << 3);
            __builtin_amdgcn_global_load_lds(
                (const __attribute__((address_space(1))) void*)sk,
                (__attribute__((address_space(3))) void*)(&KS[par][G * 8]), 16, 0, 0);
            const __hip_bfloat16* sv = vb + (size_t)rk * SEG + tile * 64 + ((gc ^ (rk & 7)) << 3);
            __builtin_amdgcn_global_load_lds(
                (const __attribute__((address_space(1))) void*)sv,
                (__attribute__((address_space(3))) void*)(&VS[par][G * 8]), 16, 0, 0);
        }
        asm volatile("s_waitcnt vmcnt(0)" ::: "memory");
        FENCED_BARRIER();

        f32x16_t st[2];
#pragma unroll
        for (int t = 0; t < 2; ++t)
#pragma unroll
            for (int r = 0; r < 16; ++r) st[t][r] = 0.f;
#pragma unroll
        for (int s = 0; s < 4; ++s) {
            int gk = s * 2 + hi;
            bf16x8_t k0 = *(const bf16x8_t*)(&KS[par][l31 * 64 + ((gk ^ (l31 & 7)) << 3)]);
            bf16x8_t k1 = *(const bf16x8_t*)(&KS[par][(32 + l31) * 64 + ((gk ^ (l31 & 7)) << 3)]);
            st[0] = __builtin_amdgcn_mfma_f32_32x32x16_bf16(k0, qf[s], st[0], 0, 0, 0);
            st[1] = __builtin_amdgcn_mfma_f32_32x32x16_bf16(k1, qf[s], st[1], 0, 0, 0);
        }

        float psum = 0.f;
#pragma unroll
        for (int t = 0; t < 2; ++t)
#pragma unroll
            for (int r = 0; r < 16; ++r) {
                float p = exp2f(st[t][r]);
                st[t][r] = p;
                psum += p;
            }
        psum += __shfl_xor(psum, 32);
        lrun += psum;

        bf16x8_t pf[4];
#pragma unroll
        for (int t = 0; t < 2; ++t) {
            unsigned wv[8], ov[8];
#pragma unroll
            for (int j = 0; j < 8; ++j) wv[j] = pk2(st[t][2 * j], st[t][2 * j + 1]);
#pragma unroll
            for (int j = 0; j < 8; ++j) ov[j] = (unsigned)__shfl_xor((int)wv[j], 32);
#pragma unroll
            for (int sh = 0; sh < 2; ++sh) {
                int b = sh * 4;
                union { unsigned u[4]; bf16x8_t v; } u8;
                u8.u[0] = hi ? ov[b + 2] : wv[b + 0];
                u8.u[1] = hi ? ov[b + 3] : wv[b + 1];
                u8.u[2] = hi ? wv[b + 2] : ov[b + 0];
                u8.u[3] = hi ? wv[b + 3] : ov[b + 1];
                pf[t * 2 + sh] = u8.v;
            }
        }

#pragma unroll
        for (int s = 0; s < 4; ++s) {
            int gk = s * 2 + hi;
            bf16x8_t v0 = *(const bf16x8_t*)(&VS[par][l31 * 64 + ((gk ^ (l31 & 7)) << 3)]);
            bf16x8_t v1 = *(const bf16x8_t*)(&VS[par][(32 + l31) * 64 + ((gk ^ (l31 & 7)) << 3)]);
            ot[0] = __builtin_amdgcn_mfma_f32_32x32x16_bf16(v0, pf[s], ot[0], 0, 0, 0);
            ot[1] = __builtin_amdgcn_mfma_f32_32x32x16_bf16(v1, pf[s], ot[1], 0, 0, 0);
        }
        FENCED_BARRIER();
    }

    // ---- cross-parity combine ----
    float* redO = (float*)KS;            // 4096 floats
    float* redL = (float*)VS;            // 128 floats
    if (par == 1) {
#pragma unroll
        for (int n = 0; n < 2; ++n)
#pragma unroll
            for (int r = 0; r < 16; ++r)
                redO[(qw * 32 + n * 16 + r) * 64 + lane] = ot[n][r];
        redL[qw * 64 + lane] = lrun;
    }
    FENCED_BARRIER();
    if (par == 1) return;
#pragma unroll
    for (int n = 0; n < 2; ++n)
#pragma unroll
        for (int r = 0; r < 16; ++r)
            ot[n][r] += redO[(qw * 32 + n * 16 + r) * 64 + lane];
    lrun += redL[qw * 64 + lane];

    // ---- epilogue (par-0 waves) ----
    float invl = 1.0f / lrun;
    ushort* Os = (ushort*)VS + 256 + qw * 2112;
#pragma unroll
    for (int n = 0; n < 2; ++n)
#pragma unroll
        for (int r = 0; r < 16; ++r) {
            int d = n * 32 + (r & 3) + 8 * (r >> 2) + 4 * hi;
            Os[d * 33 + l31] = __bfloat16_as_ushort(__float2bfloat16(ot[n][r] * invl));
        }
    {
        unsigned ow2[16];
#pragma unroll
        for (int j = 0; j < 16; ++j) {
            unsigned lo = Os[(hi * 32 + 2 * j) * 33 + l31];
            unsigned hh = Os[(hi * 32 + 2 * j + 1) * 33 + l31];
            ow2[j] = lo | (hh << 16);
        }
        uint4* gd = (uint4*)(attnb + (size_t)(t0 + l31) * D_MODEL + h * DH + hi * 32);
        gd[0] = make_uint4(ow2[0], ow2[1], ow2[2], ow2[3]);
        gd[1] = make_uint4(ow2[4], ow2[5], ow2[6], ow2[7]);
        gd[2] = make_uint4(ow2[8], ow2[9], ow2[10], ow2[11]);
        gd[3] = make_uint4(ow2[12], ow2[13], ow2[14], ow2[15]);
    }
}

// ---------------------------------------------------------------------------
extern "C" void kernel_launch(void* const* d_in, const int* in_sizes, int n_in,
                              void* d_out, int out_size, void* d_ws, size_t ws_size,
                              hipStream_t stream) {
    const float* hidden = (const float*)d_in[0];
    const float* Wqkv   = (const float*)d_in[1];
    const float* Wo     = (const float*)d_in[2];
    const int*   pos    = (const int*)d_in[3];

    char* ws = (char*)d_ws;
    __hip_bfloat16* Xb    = (__hip_bfloat16*)(ws);              // 6,291,456
    __hip_bfloat16* Wqkvt = (__hip_bfloat16*)(ws + 6291456);    // 3,538,944
    __hip_bfloat16* Wot   = (__hip_bfloat16*)(ws + 9830400);    // 1,179,648
    __hip_bfloat16* Qb    = (__hip_bfloat16*)(ws + 11010048);   // 6,291,456
    __hip_bfloat16* Kb    = (__hip_bfloat16*)(ws + 17301504);   // 6,291,456
    __hip_bfloat16* Vtb   = (__hip_bfloat16*)(ws + 23592960);   // 6,291,456
    __hip_bfloat16* attnb = (__hip_bfloat16*)(ws + 29884416);   // 6,291,456
    float2* rtab          = (float2*)(ws + 36175872);           // 1,048,576
    float* out = (float*)d_out;

    prep_inputs<<<4160, 256, 0, stream>>>(hidden, Wqkv, Wo, pos, Xb, Wqkvt, Wot, rtab);

    gemm_qkv_fused<<<dim3(18, T_TOK / 64), 256, 0, stream>>>(
        Xb, Wqkvt, rtab, Qb, Kb, Vtb);

    attn_mfma<<<768, 256, 0, stream>>>(Qb, Kb, Vtb, attnb);

    gemm_wo64<<<dim3(D_MODEL / 64, T_TOK / 64), 256, 0, stream>>>(
        attnb, Wot, out);
}

// Round 19
// 71.926 us; speedup vs baseline: 1.1287x; 1.1287x over previous
//
#include <hip/hip_runtime.h>
#include <hip/hip_bf16.h>
#include <math.h>

#define T_TOK 4096
#define D_MODEL 768
#define H_HEADS 12
#define DH 64
#define SEG 512
#define NSEG 8
#define QKV_LD 2304   // 3*D

typedef __bf16 bf16x8_t __attribute__((ext_vector_type(8)));
typedef float f32x4_t __attribute__((ext_vector_type(4)));
typedef float f32x16_t __attribute__((ext_vector_type(16)));

#define GBK 64
// Q pre-scale: 1/sqrt(64) * log2(e)  (softmax computed in base-2 space)
#define QSCALE 0.18033688011112042f

// compile-time-fenced workgroup barrier (rule #18)
#define FENCED_BARRIER()                         \
    do {                                         \
        __builtin_amdgcn_sched_barrier(0);       \
        __builtin_amdgcn_s_barrier();            \
        __builtin_amdgcn_sched_barrier(0);       \
    } while (0)

// ---------------------------------------------------------------------------
// prep: fp32->bf16 convert of X + transpose-convert of Wqkv, Wo + RoPE table
// ---------------------------------------------------------------------------
__device__ __forceinline__ void tconv_body(const float* __restrict__ in,
                                           __hip_bfloat16* __restrict__ out,
                                           int N, int K, int bx, int by, int tid,
                                           float (*tile)[65]) {
    const int k0 = by * 64;
    const int n0 = bx * 64;
    const int rr = tid >> 4;
    const int cc = (tid & 15) * 4;
#pragma unroll
    for (int i = 0; i < 4; ++i) {
        int r = i * 16 + rr;
        float4 v = *(const float4*)(in + (size_t)(k0 + r) * N + n0 + cc);
        tile[r][cc] = v.x; tile[r][cc + 1] = v.y; tile[r][cc + 2] = v.z; tile[r][cc + 3] = v.w;
    }
    __syncthreads();
#pragma unroll
    for (int i = 0; i < 4; ++i) {
        int n = i * 16 + rr;
        union { __hip_bfloat16 h[4]; ushort4 u; } o;
        o.h[0] = __float2bfloat16(tile[cc + 0][n]);
        o.h[1] = __float2bfloat16(tile[cc + 1][n]);
        o.h[2] = __float2bfloat16(tile[cc + 2][n]);
        o.h[3] = __float2bfloat16(tile[cc + 3][n]);
        *(ushort4*)(out + (size_t)(n0 + n) * K + k0 + cc) = o.u;
    }
}

__global__ __launch_bounds__(256) void prep_inputs(const float* __restrict__ hidden,
                                                   const float* __restrict__ Wqkv,
                                                   const float* __restrict__ Wo,
                                                   const int* __restrict__ pos_ids,
                                                   __hip_bfloat16* __restrict__ Xb,
                                                   __hip_bfloat16* __restrict__ Wqkvt,
                                                   __hip_bfloat16* __restrict__ Wot,
                                                   float2* __restrict__ rtab) {
    __shared__ float tile[64][65];
    const int b = blockIdx.x;
    const int tid = threadIdx.x;
    if (b < 3072) {
        int i = b * 256 + tid;
        float4 v = ((const float4*)hidden)[i];
        union { __hip_bfloat16 h[4]; ushort4 u; } o;
        o.h[0] = __float2bfloat16(v.x); o.h[1] = __float2bfloat16(v.y);
        o.h[2] = __float2bfloat16(v.z); o.h[3] = __float2bfloat16(v.w);
        ((ushort4*)Xb)[i] = o.u;
    } else if (b < 3504) {
        int lb = b - 3072;
        tconv_body(Wqkv, Wqkvt, QKV_LD, D_MODEL, lb % 36, lb / 36, tid, tile);
    } else if (b < 3648) {
        int lb = b - 3504;
        tconv_body(Wo, Wot, D_MODEL, D_MODEL, lb % 12, lb / 12, tid, tile);
    } else {
        int idx = (b - 3648) * 256 + tid;   // T*32 = 131072 exactly
        int t = idx >> 5;
        int i = idx & 31;
        float pos = (float)pos_ids[t];
        float inv_freq = powf(160000.0f, -(float)i / 32.0f);
        float s, c;
        sincosf(pos * inv_freq, &s, &c);
        rtab[idx] = make_float2(c, s);
    }
}

// ---------------------------------------------------------------------------
// QKV GEMM: 256 thr, 4 waves of 32x64, 64x128 tile. 3-buffer LDS pipeline
// with ONE barrier/iter: stage(k+2) issued AFTER barrier k (which guarantees
// both stage-k landed [vmcnt(6) before it] and buf[(k+2)%3]'s readers done).
// T2 swizzle + T1 chunked XCD remap (1152 = 8 x 144); RoPE-table epilogue.
// ---------------------------------------------------------------------------
__global__ __launch_bounds__(256) void gemm_qkv_fused(const __hip_bfloat16* __restrict__ A,
                                                      const __hip_bfloat16* __restrict__ Bt,
                                                      const float2* __restrict__ rtab,
                                                      __hip_bfloat16* __restrict__ Qb,
                                                      __hip_bfloat16* __restrict__ Kb,
                                                      __hip_bfloat16* __restrict__ Vtb) {
    __shared__ __hip_bfloat16 As[3][64 * GBK];    // 24 KB
    __shared__ __hip_bfloat16 Bs[3][128 * GBK];   // 48 KB
    const int tid = threadIdx.x;
    const int lane = tid & 63;
    const int wid = tid >> 6;          // 0..3
    const int wr = wid >> 1;           // 0..1
    const int wc = wid & 1;            // 0..1
    const int orig = blockIdx.y * 18 + blockIdx.x;   // 0..1151
    const int wg = (orig & 7) * 144 + (orig >> 3);
    const int m0 = (wg / 18) * 64;
    const int n0 = (wg % 18) * 128;
    const int K = D_MODEL;

    f32x4_t acc[2][4];
#pragma unroll
    for (int i = 0; i < 2; ++i)
#pragma unroll
        for (int j = 0; j < 4; ++j) acc[i][j] = (f32x4_t){0.f, 0.f, 0.f, 0.f};

    const int lr = lane >> 3;
    const int gc = lane & 7;
    const int swzc = (gc ^ lr) << 3;
    const int fr = lane & 15;
    const int l4 = lane >> 4;
    const int fsw = fr & 7;

// per wave: A 2 loads (16 rows) + B 4 loads (32 rows) = 6 loads/stage
#define STAGE_Q(buf_, k0_)                                                            \
    do {                                                                              \
        _Pragma("unroll")                                                             \
        for (int i_ = 0; i_ < 2; ++i_) {                                              \
            const int row_ = wid * 16 + i_ * 8;                                       \
            const __hip_bfloat16* ga_ = A + (size_t)(m0 + row_ + lr) * K + (k0_) + swzc; \
            __builtin_amdgcn_global_load_lds(                                         \
                (const __attribute__((address_space(1))) void*)ga_,                   \
                (__attribute__((address_space(3))) void*)(As[buf_] + row_ * GBK), 16, 0, 0); \
        }                                                                             \
        _Pragma("unroll")                                                             \
        for (int i_ = 0; i_ < 4; ++i_) {                                              \
            const int row_ = wid * 32 + i_ * 8;                                       \
            const __hip_bfloat16* gb_ = Bt + (size_t)(n0 + row_ + lr) * K + (k0_) + swzc; \
            __builtin_amdgcn_global_load_lds(                                         \
                (const __attribute__((address_space(1))) void*)gb_,                   \
                (__attribute__((address_space(3))) void*)(Bs[buf_] + row_ * GBK), 16, 0, 0); \
        }                                                                             \
    } while (0)

    STAGE_Q(0, 0);
    STAGE_Q(1, GBK);
#pragma unroll
    for (int kt = 0; kt < 12; ++kt) {
        const int cur = kt % 3;
        if (kt < 11) {
            asm volatile("s_waitcnt vmcnt(6)" ::: "memory");   // stage-k landed
        } else {
            asm volatile("s_waitcnt vmcnt(0)" ::: "memory");
        }
        FENCED_BARRIER();
        if (kt < 10) STAGE_Q((kt + 2) % 3, (kt + 2) * GBK);    // safe: buf read last at iter k-1
#pragma unroll
        for (int kk = 0; kk < 2; ++kk) {
            const int rg = ((kk * 4 + l4) ^ fsw) << 3;
            bf16x8_t af[2], bfr[4];
#pragma unroll
            for (int mi = 0; mi < 2; ++mi)
                af[mi] = *(const bf16x8_t*)(As[cur] + (wr * 32 + mi * 16 + fr) * GBK + rg);
#pragma unroll
            for (int ni = 0; ni < 4; ++ni)
                bfr[ni] = *(const bf16x8_t*)(Bs[cur] + (wc * 64 + ni * 16 + fr) * GBK + rg);
#pragma unroll
            for (int mi = 0; mi < 2; ++mi)
#pragma unroll
                for (int ni = 0; ni < 4; ++ni)
                    acc[mi][ni] = __builtin_amdgcn_mfma_f32_16x16x32_bf16(
                        af[mi], bfr[ni], acc[mi][ni], 0, 0, 0);
        }
    }
#undef STAGE_Q

    // ---- fused epilogue (identical to rounds 16/17) ----
    const int colbase = n0 + wc * 64;
    const int chunk = colbase >> 6;          // 0..35
    const int part = chunk / H_HEADS;        // 0=q 1=k 2=v
    const int h = chunk % H_HEADS;
    const int trow0 = m0 + wr * 32;

    if (part == 2) {
        const int seg = trow0 >> 9;
        const int key0 = (trow0 & 511) + l4 * 4;
        __hip_bfloat16* vdst = Vtb + ((size_t)(h * NSEG + seg) * DH) * SEG;
#pragma unroll
        for (int mi = 0; mi < 2; ++mi)
#pragma unroll
            for (int ni = 0; ni < 4; ++ni) {
                int d = ni * 16 + fr;
                union { __hip_bfloat16 h2[4]; ushort4 u; } o;
#pragma unroll
                for (int j = 0; j < 4; ++j) o.h2[j] = __float2bfloat16(acc[mi][ni][j]);
                *(ushort4*)(vdst + (size_t)d * SEG + key0 + mi * 16) = o.u;
            }
    } else {
        __hip_bfloat16* dst = (part == 0) ? Qb : Kb;
        const float scale = (part == 0) ? QSCALE : 1.0f;
#pragma unroll
        for (int mi = 0; mi < 2; ++mi)
#pragma unroll
            for (int j = 0; j < 4; ++j) {
                int t = trow0 + mi * 16 + l4 * 4 + j;
                const float2* tb = rtab + (size_t)t * 32;
                float2 cs0 = tb[fr];
                float2 cs1 = tb[16 + fr];
                __hip_bfloat16* op = dst + ((size_t)h * T_TOK + t) * DH;
                float x1, x2;
                x1 = acc[mi][0][j]; x2 = acc[mi][2][j];
                op[fr]      = __float2bfloat16((x1 * cs0.x - x2 * cs0.y) * scale);
                op[fr + 32] = __float2bfloat16((x2 * cs0.x + x1 * cs0.y) * scale);
                x1 = acc[mi][1][j]; x2 = acc[mi][3][j];
                op[16 + fr] = __float2bfloat16((x1 * cs1.x - x2 * cs1.y) * scale);
                op[48 + fr] = __float2bfloat16((x2 * cs1.x + x1 * cs1.y) * scale);
            }
    }
}

// ---------------------------------------------------------------------------
// Wo GEMM: 64x64 tile, 256 thr, 768 blocks; T2 swizzle + T1 XCD remap
// ---------------------------------------------------------------------------
__global__ __launch_bounds__(256) void gemm_wo64(const __hip_bfloat16* __restrict__ A,
                                                 const __hip_bfloat16* __restrict__ Bt,
                                                 float* __restrict__ C) {
    __shared__ __hip_bfloat16 As[2][64 * GBK];
    __shared__ __hip_bfloat16 Bs[2][64 * GBK];
    const int tid = threadIdx.x;
    const int lane = tid & 63;
    const int wid = tid >> 6;
    const int wr = wid >> 1, wc = wid & 1;
    const int orig = blockIdx.y * 12 + blockIdx.x;   // 0..767
    const int wg = (orig & 7) * 96 + (orig >> 3);
    const int m0 = (wg / 12) * 64;
    const int n0 = (wg % 12) * 64;
    const int K = D_MODEL;
    const int N = D_MODEL;

    f32x4_t acc[2][2];
#pragma unroll
    for (int i = 0; i < 2; ++i)
#pragma unroll
        for (int j = 0; j < 2; ++j) acc[i][j] = (f32x4_t){0.f, 0.f, 0.f, 0.f};

    const int lr = lane >> 3;
    const int gc = lane & 7;
    const int swzc = (gc ^ lr) << 3;
    const int fr = lane & 15;
    const int l4 = lane >> 4;
    const int fsw = fr & 7;

#define STAGE_W(buf_, k0_)                                                            \
    do {                                                                              \
        _Pragma("unroll")                                                             \
        for (int i_ = 0; i_ < 2; ++i_) {                                              \
            const int row_ = i_ * 32 + wid * 8;                                       \
            const __hip_bfloat16* ga_ = A + (size_t)(m0 + row_ + lr) * K + (k0_) + swzc; \
            __builtin_amdgcn_global_load_lds(                                         \
                (const __attribute__((address_space(1))) void*)ga_,                   \
                (__attribute__((address_space(3))) void*)(As[buf_] + row_ * GBK), 16, 0, 0); \
            const __hip_bfloat16* gb_ = Bt + (size_t)(n0 + row_ + lr) * K + (k0_) + swzc; \
            __builtin_amdgcn_global_load_lds(                                         \
                (const __attribute__((address_space(1))) void*)gb_,                   \
                (__attribute__((address_space(3))) void*)(Bs[buf_] + row_ * GBK), 16, 0, 0); \
        }                                                                             \
    } while (0)

    const int NKT = K / GBK;   // 12
    STAGE_W(0, 0);
    for (int kt = 0; kt < NKT; ++kt) {
        const int cur = kt & 1;
        if (kt < NKT - 1) {
            STAGE_W(cur ^ 1, (kt + 1) * GBK);
            asm volatile("s_waitcnt vmcnt(4)" ::: "memory");
        } else {
            asm volatile("s_waitcnt vmcnt(0)" ::: "memory");
        }
        FENCED_BARRIER();
#pragma unroll
        for (int kk = 0; kk < 2; ++kk) {
            const int rg = ((kk * 4 + l4) ^ fsw) << 3;
            bf16x8_t af[2], bfr[2];
#pragma unroll
            for (int mi = 0; mi < 2; ++mi)
                af[mi] = *(const bf16x8_t*)(As[cur] + (wr * 32 + mi * 16 + fr) * GBK + rg);
#pragma unroll
            for (int ni = 0; ni < 2; ++ni)
                bfr[ni] = *(const bf16x8_t*)(Bs[cur] + (wc * 32 + ni * 16 + fr) * GBK + rg);
#pragma unroll
            for (int mi = 0; mi < 2; ++mi)
#pragma unroll
                for (int ni = 0; ni < 2; ++ni)
                    acc[mi][ni] = __builtin_amdgcn_mfma_f32_16x16x32_bf16(
                        af[mi], bfr[ni], acc[mi][ni], 0, 0, 0);
        }
        asm volatile("" ::: "memory");
        FENCED_BARRIER();
    }
#undef STAGE_W

    float* Cb = C + (size_t)(m0 + wr * 32) * N + n0 + wc * 32;
#pragma unroll
    for (int mi = 0; mi < 2; ++mi)
#pragma unroll
        for (int ni = 0; ni < 2; ++ni)
#pragma unroll
            for (int j = 0; j < 4; ++j) {
                int r = mi * 16 + (lane >> 4) * 4 + j;
                Cb[(size_t)r * N + ni * 16 + fr] = acc[mi][ni][j];
            }
}

// ---------------- parity-split swapped-QK flash attention -------------------
__device__ __forceinline__ unsigned pk2(float a, float b) {
    unsigned ua = (unsigned)__bfloat16_as_ushort(__float2bfloat16(a));
    unsigned ub = (unsigned)__bfloat16_as_ushort(__float2bfloat16(b));
    return ua | (ub << 16);
}

__global__ __launch_bounds__(256) void attn_mfma(const __hip_bfloat16* __restrict__ Qb,
                                                 const __hip_bfloat16* __restrict__ Kb,
                                                 const __hip_bfloat16* __restrict__ Vtb,
                                                 __hip_bfloat16* __restrict__ attnb) {
    __shared__ __hip_bfloat16 KS[2][64 * 64];   // [parity]
    __shared__ __hip_bfloat16 VS[2][64 * 64];

    const int tid = threadIdx.x;
    const int lane = tid & 63;
    const int w = tid >> 6;        // 0..3
    const int qw = w & 1;          // q-row half
    const int par = w >> 1;        // kv parity
    const int hi = lane >> 5;
    const int l31 = lane & 31;
    const int orig = blockIdx.x;                 // 0..767
    const int wg = (orig & 7) * 96 + (orig >> 3);
    const int qt = wg & 7;
    const int hs = wg >> 3;
    const int h = hs % H_HEADS;
    const int seg = hs / H_HEADS;
    const int t0 = seg * SEG + qt * 64 + qw * 32;

    const __hip_bfloat16* kb = Kb + ((size_t)h * T_TOK + seg * SEG) * DH;
    const __hip_bfloat16* vb = Vtb + (size_t)(h * NSEG + seg) * DH * SEG;

    bf16x8_t qf[4];
    {
        const __hip_bfloat16* qp = Qb + ((size_t)h * T_TOK + t0 + l31) * DH + hi * 8;
#pragma unroll
        for (int s = 0; s < 4; ++s) qf[s] = *(const bf16x8_t*)(qp + s * 16);
    }

    const int gr = lane >> 3;
    const int gc = lane & 7;

    f32x16_t ot[2];
#pragma unroll
    for (int n = 0; n < 2; ++n)
#pragma unroll
        for (int r = 0; r < 16; ++r) ot[n][r] = 0.f;
    float lrun = 0.f;

    for (int it = 0; it < 4; ++it) {
        const int tile = 2 * it + par;
#pragma unroll
        for (int i = 0; i < 4; ++i) {
            int G = i * 128 + qw * 64;
            int rk = (G >> 3) + gr;
            const __hip_bfloat16* sk = kb + (size_t)(tile * 64 + rk) * DH + ((gc ^ (rk & 7)) << 3);
            __builtin_amdgcn_global_load_lds(
                (const __attribute__((address_space(1))) void*)sk,
                (__attribute__((address_space(3))) void*)(&KS[par][G * 8]), 16, 0, 0);
            const __hip_bfloat16* sv = vb + (size_t)rk * SEG + tile * 64 + ((gc ^ (rk & 7)) << 3);
            __builtin_amdgcn_global_load_lds(
                (const __attribute__((address_space(1))) void*)sv,
                (__attribute__((address_space(3))) void*)(&VS[par][G * 8]), 16, 0, 0);
        }
        asm volatile("s_waitcnt vmcnt(0)" ::: "memory");
        FENCED_BARRIER();

        f32x16_t st[2];
#pragma unroll
        for (int t = 0; t < 2; ++t)
#pragma unroll
            for (int r = 0; r < 16; ++r) st[t][r] = 0.f;
#pragma unroll
        for (int s = 0; s < 4; ++s) {
            int gk = s * 2 + hi;
            bf16x8_t k0 = *(const bf16x8_t*)(&KS[par][l31 * 64 + ((gk ^ (l31 & 7)) << 3)]);
            bf16x8_t k1 = *(const bf16x8_t*)(&KS[par][(32 + l31) * 64 + ((gk ^ (l31 & 7)) << 3)]);
            st[0] = __builtin_amdgcn_mfma_f32_32x32x16_bf16(k0, qf[s], st[0], 0, 0, 0);
            st[1] = __builtin_amdgcn_mfma_f32_32x32x16_bf16(k1, qf[s], st[1], 0, 0, 0);
        }

        float psum = 0.f;
#pragma unroll
        for (int t = 0; t < 2; ++t)
#pragma unroll
            for (int r = 0; r < 16; ++r) {
                float p = exp2f(st[t][r]);
                st[t][r] = p;
                psum += p;
            }
        psum += __shfl_xor(psum, 32);
        lrun += psum;

        bf16x8_t pf[4];
#pragma unroll
        for (int t = 0; t < 2; ++t) {
            unsigned wv[8], ov[8];
#pragma unroll
            for (int j = 0; j < 8; ++j) wv[j] = pk2(st[t][2 * j], st[t][2 * j + 1]);
#pragma unroll
            for (int j = 0; j < 8; ++j) ov[j] = (unsigned)__shfl_xor((int)wv[j], 32);
#pragma unroll
            for (int sh = 0; sh < 2; ++sh) {
                int b = sh * 4;
                union { unsigned u[4]; bf16x8_t v; } u8;
                u8.u[0] = hi ? ov[b + 2] : wv[b + 0];
                u8.u[1] = hi ? ov[b + 3] : wv[b + 1];
                u8.u[2] = hi ? wv[b + 2] : ov[b + 0];
                u8.u[3] = hi ? wv[b + 3] : ov[b + 1];
                pf[t * 2 + sh] = u8.v;
            }
        }

#pragma unroll
        for (int s = 0; s < 4; ++s) {
            int gk = s * 2 + hi;
            bf16x8_t v0 = *(const bf16x8_t*)(&VS[par][l31 * 64 + ((gk ^ (l31 & 7)) << 3)]);
            bf16x8_t v1 = *(const bf16x8_t*)(&VS[par][(32 + l31) * 64 + ((gk ^ (l31 & 7)) << 3)]);
            ot[0] = __builtin_amdgcn_mfma_f32_32x32x16_bf16(v0, pf[s], ot[0], 0, 0, 0);
            ot[1] = __builtin_amdgcn_mfma_f32_32x32x16_bf16(v1, pf[s], ot[1], 0, 0, 0);
        }
        FENCED_BARRIER();
    }

    // ---- cross-parity combine ----
    float* redO = (float*)KS;            // 4096 floats
    float* redL = (float*)VS;            // 128 floats
    if (par == 1) {
#pragma unroll
        for (int n = 0; n < 2; ++n)
#pragma unroll
            for (int r = 0; r < 16; ++r)
                redO[(qw * 32 + n * 16 + r) * 64 + lane] = ot[n][r];
        redL[qw * 64 + lane] = lrun;
    }
    FENCED_BARRIER();
    if (par == 1) return;
#pragma unroll
    for (int n = 0; n < 2; ++n)
#pragma unroll
        for (int r = 0; r < 16; ++r)
            ot[n][r] += redO[(qw * 32 + n * 16 + r) * 64 + lane];
    lrun += redL[qw * 64 + lane];

    // ---- epilogue (par-0 waves) ----
    float invl = 1.0f / lrun;
    ushort* Os = (ushort*)VS + 256 + qw * 2112;
#pragma unroll
    for (int n = 0; n < 2; ++n)
#pragma unroll
        for (int r = 0; r < 16; ++r) {
            int d = n * 32 + (r & 3) + 8 * (r >> 2) + 4 * hi;
            Os[d * 33 + l31] = __bfloat16_as_ushort(__float2bfloat16(ot[n][r] * invl));
        }
    {
        unsigned ow2[16];
#pragma unroll
        for (int j = 0; j < 16; ++j) {
            unsigned lo = Os[(hi * 32 + 2 * j) * 33 + l31];
            unsigned hh = Os[(hi * 32 + 2 * j + 1) * 33 + l31];
            ow2[j] = lo | (hh << 16);
        }
        uint4* gd = (uint4*)(attnb + (size_t)(t0 + l31) * D_MODEL + h * DH + hi * 32);
        gd[0] = make_uint4(ow2[0], ow2[1], ow2[2], ow2[3]);
        gd[1] = make_uint4(ow2[4], ow2[5], ow2[6], ow2[7]);
        gd[2] = make_uint4(ow2[8], ow2[9], ow2[10], ow2[11]);
        gd[3] = make_uint4(ow2[12], ow2[13], ow2[14], ow2[15]);
    }
}

// ---------------------------------------------------------------------------
extern "C" void kernel_launch(void* const* d_in, const int* in_sizes, int n_in,
                              void* d_out, int out_size, void* d_ws, size_t ws_size,
                              hipStream_t stream) {
    const float* hidden = (const float*)d_in[0];
    const float* Wqkv   = (const float*)d_in[1];
    const float* Wo     = (const float*)d_in[2];
    const int*   pos    = (const int*)d_in[3];

    char* ws = (char*)d_ws;
    __hip_bfloat16* Xb    = (__hip_bfloat16*)(ws);              // 6,291,456
    __hip_bfloat16* Wqkvt = (__hip_bfloat16*)(ws + 6291456);    // 3,538,944
    __hip_bfloat16* Wot   = (__hip_bfloat16*)(ws + 9830400);    // 1,179,648
    __hip_bfloat16* Qb    = (__hip_bfloat16*)(ws + 11010048);   // 6,291,456
    __hip_bfloat16* Kb    = (__hip_bfloat16*)(ws + 17301504);   // 6,291,456
    __hip_bfloat16* Vtb   = (__hip_bfloat16*)(ws + 23592960);   // 6,291,456
    __hip_bfloat16* attnb = (__hip_bfloat16*)(ws + 29884416);   // 6,291,456
    float2* rtab          = (float2*)(ws + 36175872);           // 1,048,576
    float* out = (float*)d_out;

    prep_inputs<<<4160, 256, 0, stream>>>(hidden, Wqkv, Wo, pos, Xb, Wqkvt, Wot, rtab);

    gemm_qkv_fused<<<dim3(18, T_TOK / 64), 256, 0, stream>>>(
        Xb, Wqkvt, rtab, Qb, Kb, Vtb);

    attn_mfma<<<768, 256, 0, stream>>>(Qb, Kb, Vtb, attnb);

    gemm_wo64<<<dim3(D_MODEL / 64, T_TOK / 64), 256, 0, stream>>>(
        attnb, Wot, out);
}

// Round 20
// 65.711 us; speedup vs baseline: 1.2354x; 1.0946x over previous
//
#include <hip/hip_runtime.h>
#include <hip/hip_bf16.h>
#include <math.h>

#define T_TOK 4096
#define D_MODEL 768
#define H_HEADS 12
#define DH 64
#define SEG 512
#define NSEG 8
#define QKV_LD 2304   // 3*D

typedef __bf16 bf16x8_t __attribute__((ext_vector_type(8)));
typedef float f32x4_t __attribute__((ext_vector_type(4)));
typedef float f32x16_t __attribute__((ext_vector_type(16)));

#define GBK 64
// Q pre-scale: 1/sqrt(64) * log2(e)  (softmax computed in base-2 space)
#define QSCALE 0.18033688011112042f

// compile-time-fenced workgroup barrier (rule #18)
#define FENCED_BARRIER()                         \
    do {                                         \
        __builtin_amdgcn_sched_barrier(0);       \
        __builtin_amdgcn_s_barrier();            \
        __builtin_amdgcn_sched_barrier(0);       \
    } while (0)

// ---------------------------------------------------------------------------
// prep: fp32->bf16 convert of X + transpose-convert of Wqkv, Wo + RoPE table
// ---------------------------------------------------------------------------
__device__ __forceinline__ void tconv_body(const float* __restrict__ in,
                                           __hip_bfloat16* __restrict__ out,
                                           int N, int K, int bx, int by, int tid,
                                           float (*tile)[65]) {
    const int k0 = by * 64;
    const int n0 = bx * 64;
    const int rr = tid >> 4;
    const int cc = (tid & 15) * 4;
#pragma unroll
    for (int i = 0; i < 4; ++i) {
        int r = i * 16 + rr;
        float4 v = *(const float4*)(in + (size_t)(k0 + r) * N + n0 + cc);
        tile[r][cc] = v.x; tile[r][cc + 1] = v.y; tile[r][cc + 2] = v.z; tile[r][cc + 3] = v.w;
    }
    __syncthreads();
#pragma unroll
    for (int i = 0; i < 4; ++i) {
        int n = i * 16 + rr;
        union { __hip_bfloat16 h[4]; ushort4 u; } o;
        o.h[0] = __float2bfloat16(tile[cc + 0][n]);
        o.h[1] = __float2bfloat16(tile[cc + 1][n]);
        o.h[2] = __float2bfloat16(tile[cc + 2][n]);
        o.h[3] = __float2bfloat16(tile[cc + 3][n]);
        *(ushort4*)(out + (size_t)(n0 + n) * K + k0 + cc) = o.u;
    }
}

__global__ __launch_bounds__(256) void prep_inputs(const float* __restrict__ hidden,
                                                   const float* __restrict__ Wqkv,
                                                   const float* __restrict__ Wo,
                                                   const int* __restrict__ pos_ids,
                                                   __hip_bfloat16* __restrict__ Xb,
                                                   __hip_bfloat16* __restrict__ Wqkvt,
                                                   __hip_bfloat16* __restrict__ Wot,
                                                   float2* __restrict__ rtab) {
    __shared__ float tile[64][65];
    const int b = blockIdx.x;
    const int tid = threadIdx.x;
    if (b < 3072) {
        int i = b * 256 + tid;
        float4 v = ((const float4*)hidden)[i];
        union { __hip_bfloat16 h[4]; ushort4 u; } o;
        o.h[0] = __float2bfloat16(v.x); o.h[1] = __float2bfloat16(v.y);
        o.h[2] = __float2bfloat16(v.z); o.h[3] = __float2bfloat16(v.w);
        ((ushort4*)Xb)[i] = o.u;
    } else if (b < 3504) {
        int lb = b - 3072;
        tconv_body(Wqkv, Wqkvt, QKV_LD, D_MODEL, lb % 36, lb / 36, tid, tile);
    } else if (b < 3648) {
        int lb = b - 3504;
        tconv_body(Wo, Wot, D_MODEL, D_MODEL, lb % 12, lb / 12, tid, tile);
    } else {
        int idx = (b - 3648) * 256 + tid;   // T*32 = 131072 exactly
        int t = idx >> 5;
        int i = idx & 31;
        float pos = (float)pos_ids[t];
        float inv_freq = powf(160000.0f, -(float)i / 32.0f);
        float s, c;
        sincosf(pos * inv_freq, &s, &c);
        rtab[idx] = make_float2(c, s);
    }
}

// ---------------------------------------------------------------------------
// QKV GEMM: 256 thr, 4 waves of 32x64, 64x128 tile (48KB LDS, 3 blocks/CU,
// grid 1152). T2 swizzle + T1 chunked XCD remap; RoPE table epilogue.
// ---------------------------------------------------------------------------
__global__ __launch_bounds__(256) void gemm_qkv_fused(const __hip_bfloat16* __restrict__ A,
                                                      const __hip_bfloat16* __restrict__ Bt,
                                                      const float2* __restrict__ rtab,
                                                      __hip_bfloat16* __restrict__ Qb,
                                                      __hip_bfloat16* __restrict__ Kb,
                                                      __hip_bfloat16* __restrict__ Vtb) {
    __shared__ __hip_bfloat16 As[2][64 * GBK];    // 16 KB
    __shared__ __hip_bfloat16 Bs[2][128 * GBK];   // 32 KB
    const int tid = threadIdx.x;
    const int lane = tid & 63;
    const int wid = tid >> 6;          // 0..3
    const int wr = wid >> 1;           // 0..1
    const int wc = wid & 1;            // 0..1
    const int orig = blockIdx.y * 18 + blockIdx.x;   // 0..1151
    const int wg = (orig & 7) * 144 + (orig >> 3);
    const int m0 = (wg / 18) * 64;
    const int n0 = (wg % 18) * 128;
    const int K = D_MODEL;

    f32x4_t acc[2][4];
#pragma unroll
    for (int i = 0; i < 2; ++i)
#pragma unroll
        for (int j = 0; j < 4; ++j) acc[i][j] = (f32x4_t){0.f, 0.f, 0.f, 0.f};

    const int lr = lane >> 3;
    const int gc = lane & 7;
    const int swzc = (gc ^ lr) << 3;
    const int fr = lane & 15;
    const int l4 = lane >> 4;
    const int fsw = fr & 7;

#define STAGE_Q(buf_, k0_)                                                            \
    do {                                                                              \
        _Pragma("unroll")                                                             \
        for (int i_ = 0; i_ < 2; ++i_) {                                              \
            const int row_ = wid * 16 + i_ * 8;                                       \
            const __hip_bfloat16* ga_ = A + (size_t)(m0 + row_ + lr) * K + (k0_) + swzc; \
            __builtin_amdgcn_global_load_lds(                                         \
                (const __attribute__((address_space(1))) void*)ga_,                   \
                (__attribute__((address_space(3))) void*)(As[buf_] + row_ * GBK), 16, 0, 0); \
        }                                                                             \
        _Pragma("unroll")                                                             \
        for (int i_ = 0; i_ < 4; ++i_) {                                              \
            const int row_ = wid * 32 + i_ * 8;                                       \
            const __hip_bfloat16* gb_ = Bt + (size_t)(n0 + row_ + lr) * K + (k0_) + swzc; \
            __builtin_amdgcn_global_load_lds(                                         \
                (const __attribute__((address_space(1))) void*)gb_,                   \
                (__attribute__((address_space(3))) void*)(Bs[buf_] + row_ * GBK), 16, 0, 0); \
        }                                                                             \
    } while (0)

    const int NKT = K / GBK;   // 12
    STAGE_Q(0, 0);
    for (int kt = 0; kt < NKT; ++kt) {
        const int cur = kt & 1;
        if (kt < NKT - 1) {
            STAGE_Q(cur ^ 1, (kt + 1) * GBK);
            asm volatile("s_waitcnt vmcnt(6)" ::: "memory");
        } else {
            asm volatile("s_waitcnt vmcnt(0)" ::: "memory");
        }
        FENCED_BARRIER();
#pragma unroll
        for (int kk = 0; kk < 2; ++kk) {
            const int rg = ((kk * 4 + l4) ^ fsw) << 3;
            bf16x8_t af[2], bfr[4];
#pragma unroll
            for (int mi = 0; mi < 2; ++mi)
                af[mi] = *(const bf16x8_t*)(As[cur] + (wr * 32 + mi * 16 + fr) * GBK + rg);
#pragma unroll
            for (int ni = 0; ni < 4; ++ni)
                bfr[ni] = *(const bf16x8_t*)(Bs[cur] + (wc * 64 + ni * 16 + fr) * GBK + rg);
#pragma unroll
            for (int mi = 0; mi < 2; ++mi)
#pragma unroll
                for (int ni = 0; ni < 4; ++ni)
                    acc[mi][ni] = __builtin_amdgcn_mfma_f32_16x16x32_bf16(
                        af[mi], bfr[ni], acc[mi][ni], 0, 0, 0);
        }
        asm volatile("" ::: "memory");
        FENCED_BARRIER();
    }
#undef STAGE_Q

    // ---- fused epilogue ----
    const int colbase = n0 + wc * 64;
    const int chunk = colbase >> 6;          // 0..35
    const int part = chunk / H_HEADS;        // 0=q 1=k 2=v
    const int h = chunk % H_HEADS;
    const int trow0 = m0 + wr * 32;

    if (part == 2) {
        const int seg = trow0 >> 9;
        const int key0 = (trow0 & 511) + l4 * 4;
        __hip_bfloat16* vdst = Vtb + ((size_t)(h * NSEG + seg) * DH) * SEG;
#pragma unroll
        for (int mi = 0; mi < 2; ++mi)
#pragma unroll
            for (int ni = 0; ni < 4; ++ni) {
                int d = ni * 16 + fr;
                union { __hip_bfloat16 h2[4]; ushort4 u; } o;
#pragma unroll
                for (int j = 0; j < 4; ++j) o.h2[j] = __float2bfloat16(acc[mi][ni][j]);
                *(ushort4*)(vdst + (size_t)d * SEG + key0 + mi * 16) = o.u;
            }
    } else {
        __hip_bfloat16* dst = (part == 0) ? Qb : Kb;
        const float scale = (part == 0) ? QSCALE : 1.0f;
#pragma unroll
        for (int mi = 0; mi < 2; ++mi)
#pragma unroll
            for (int j = 0; j < 4; ++j) {
                int t = trow0 + mi * 16 + l4 * 4 + j;
                const float2* tb = rtab + (size_t)t * 32;
                float2 cs0 = tb[fr];
                float2 cs1 = tb[16 + fr];
                __hip_bfloat16* op = dst + ((size_t)h * T_TOK + t) * DH;
                float x1, x2;
                x1 = acc[mi][0][j]; x2 = acc[mi][2][j];
                op[fr]      = __float2bfloat16((x1 * cs0.x - x2 * cs0.y) * scale);
                op[fr + 32] = __float2bfloat16((x2 * cs0.x + x1 * cs0.y) * scale);
                x1 = acc[mi][1][j]; x2 = acc[mi][3][j];
                op[16 + fr] = __float2bfloat16((x1 * cs1.x - x2 * cs1.y) * scale);
                op[48 + fr] = __float2bfloat16((x2 * cs1.x + x1 * cs1.y) * scale);
            }
    }
}

// ---------------------------------------------------------------------------
// Wo GEMM: 64x64 tile, 256 thr, 768 blocks; T2 swizzle + T1 XCD remap
// ---------------------------------------------------------------------------
__global__ __launch_bounds__(256) void gemm_wo64(const __hip_bfloat16* __restrict__ A,
                                                 const __hip_bfloat16* __restrict__ Bt,
                                                 float* __restrict__ C) {
    __shared__ __hip_bfloat16 As[2][64 * GBK];
    __shared__ __hip_bfloat16 Bs[2][64 * GBK];
    const int tid = threadIdx.x;
    const int lane = tid & 63;
    const int wid = tid >> 6;
    const int wr = wid >> 1, wc = wid & 1;
    const int orig = blockIdx.y * 12 + blockIdx.x;   // 0..767
    const int wg = (orig & 7) * 96 + (orig >> 3);
    const int m0 = (wg / 12) * 64;
    const int n0 = (wg % 12) * 64;
    const int K = D_MODEL;
    const int N = D_MODEL;

    f32x4_t acc[2][2];
#pragma unroll
    for (int i = 0; i < 2; ++i)
#pragma unroll
        for (int j = 0; j < 2; ++j) acc[i][j] = (f32x4_t){0.f, 0.f, 0.f, 0.f};

    const int lr = lane >> 3;
    const int gc = lane & 7;
    const int swzc = (gc ^ lr) << 3;
    const int fr = lane & 15;
    const int l4 = lane >> 4;
    const int fsw = fr & 7;

#define STAGE_W(buf_, k0_)                                                            \
    do {                                                                              \
        _Pragma("unroll")                                                             \
        for (int i_ = 0; i_ < 2; ++i_) {                                              \
            const int row_ = i_ * 32 + wid * 8;                                       \
            const __hip_bfloat16* ga_ = A + (size_t)(m0 + row_ + lr) * K + (k0_) + swzc; \
            __builtin_amdgcn_global_load_lds(                                         \
                (const __attribute__((address_space(1))) void*)ga_,                   \
                (__attribute__((address_space(3))) void*)(As[buf_] + row_ * GBK), 16, 0, 0); \
            const __hip_bfloat16* gb_ = Bt + (size_t)(n0 + row_ + lr) * K + (k0_) + swzc; \
            __builtin_amdgcn_global_load_lds(                                         \
                (const __attribute__((address_space(1))) void*)gb_,                   \
                (__attribute__((address_space(3))) void*)(Bs[buf_] + row_ * GBK), 16, 0, 0); \
        }                                                                             \
    } while (0)

    const int NKT = K / GBK;   // 12
    STAGE_W(0, 0);
    for (int kt = 0; kt < NKT; ++kt) {
        const int cur = kt & 1;
        if (kt < NKT - 1) {
            STAGE_W(cur ^ 1, (kt + 1) * GBK);
            asm volatile("s_waitcnt vmcnt(4)" ::: "memory");
        } else {
            asm volatile("s_waitcnt vmcnt(0)" ::: "memory");
        }
        FENCED_BARRIER();
#pragma unroll
        for (int kk = 0; kk < 2; ++kk) {
            const int rg = ((kk * 4 + l4) ^ fsw) << 3;
            bf16x8_t af[2], bfr[2];
#pragma unroll
            for (int mi = 0; mi < 2; ++mi)
                af[mi] = *(const bf16x8_t*)(As[cur] + (wr * 32 + mi * 16 + fr) * GBK + rg);
#pragma unroll
            for (int ni = 0; ni < 2; ++ni)
                bfr[ni] = *(const bf16x8_t*)(Bs[cur] + (wc * 32 + ni * 16 + fr) * GBK + rg);
#pragma unroll
            for (int mi = 0; mi < 2; ++mi)
#pragma unroll
                for (int ni = 0; ni < 2; ++ni)
                    acc[mi][ni] = __builtin_amdgcn_mfma_f32_16x16x32_bf16(
                        af[mi], bfr[ni], acc[mi][ni], 0, 0, 0);
        }
        asm volatile("" ::: "memory");
        FENCED_BARRIER();
    }
#undef STAGE_W

    float* Cb = C + (size_t)(m0 + wr * 32) * N + n0 + wc * 32;
#pragma unroll
    for (int mi = 0; mi < 2; ++mi)
#pragma unroll
        for (int ni = 0; ni < 2; ++ni)
#pragma unroll
            for (int j = 0; j < 4; ++j) {
                int r = mi * 16 + (lane >> 4) * 4 + j;
                Cb[(size_t)r * N + ni * 16 + fr] = acc[mi][ni][j];
            }
}

// ---------------- parity-split swapped-QK flash attention -------------------
// Max-free base-2 softmax is order-independent -> waves split the KV dim:
// 4 waves = (q-half qw) x (kv-parity par); parity p does tiles {p,p+2,p+4,p+6}
// (4 serial iters instead of 8), partials (O,l) combined via LDS at the end.
__device__ __forceinline__ unsigned pk2(float a, float b) {
    unsigned ua = (unsigned)__bfloat16_as_ushort(__float2bfloat16(a));
    unsigned ub = (unsigned)__bfloat16_as_ushort(__float2bfloat16(b));
    return ua | (ub << 16);
}

__global__ __launch_bounds__(256) void attn_mfma(const __hip_bfloat16* __restrict__ Qb,
                                                 const __hip_bfloat16* __restrict__ Kb,
                                                 const __hip_bfloat16* __restrict__ Vtb,
                                                 __hip_bfloat16* __restrict__ attnb) {
    __shared__ __hip_bfloat16 KS[2][64 * 64];   // [parity]
    __shared__ __hip_bfloat16 VS[2][64 * 64];

    const int tid = threadIdx.x;
    const int lane = tid & 63;
    const int w = tid >> 6;        // 0..3
    const int qw = w & 1;          // q-row half
    const int par = w >> 1;        // kv parity
    const int hi = lane >> 5;
    const int l31 = lane & 31;
    const int orig = blockIdx.x;                 // 0..767
    const int wg = (orig & 7) * 96 + (orig >> 3);
    const int qt = wg & 7;
    const int hs = wg >> 3;
    const int h = hs % H_HEADS;
    const int seg = hs / H_HEADS;
    const int t0 = seg * SEG + qt * 64 + qw * 32;

    const __hip_bfloat16* kb = Kb + ((size_t)h * T_TOK + seg * SEG) * DH;
    const __hip_bfloat16* vb = Vtb + (size_t)(h * NSEG + seg) * DH * SEG;

    bf16x8_t qf[4];
    {
        const __hip_bfloat16* qp = Qb + ((size_t)h * T_TOK + t0 + l31) * DH + hi * 8;
#pragma unroll
        for (int s = 0; s < 4; ++s) qf[s] = *(const bf16x8_t*)(qp + s * 16);
    }

    const int gr = lane >> 3;
    const int gc = lane & 7;

    f32x16_t ot[2];
#pragma unroll
    for (int n = 0; n < 2; ++n)
#pragma unroll
        for (int r = 0; r < 16; ++r) ot[n][r] = 0.f;
    float lrun = 0.f;

    for (int it = 0; it < 4; ++it) {
        const int tile = 2 * it + par;
#pragma unroll
        for (int i = 0; i < 4; ++i) {
            int G = i * 128 + qw * 64;
            int rk = (G >> 3) + gr;
            const __hip_bfloat16* sk = kb + (size_t)(tile * 64 + rk) * DH + ((gc ^ (rk & 7)) << 3);
            __builtin_amdgcn_global_load_lds(
                (const __attribute__((address_space(1))) void*)sk,
                (__attribute__((address_space(3))) void*)(&KS[par][G * 8]), 16, 0, 0);
            const __hip_bfloat16* sv = vb + (size_t)rk * SEG + tile * 64 + ((gc ^ (rk & 7)) << 3);
            __builtin_amdgcn_global_load_lds(
                (const __attribute__((address_space(1))) void*)sv,
                (__attribute__((address_space(3))) void*)(&VS[par][G * 8]), 16, 0, 0);
        }
        asm volatile("s_waitcnt vmcnt(0)" ::: "memory");
        FENCED_BARRIER();

        f32x16_t st[2];
#pragma unroll
        for (int t = 0; t < 2; ++t)
#pragma unroll
            for (int r = 0; r < 16; ++r) st[t][r] = 0.f;
#pragma unroll
        for (int s = 0; s < 4; ++s) {
            int gk = s * 2 + hi;
            bf16x8_t k0 = *(const bf16x8_t*)(&KS[par][l31 * 64 + ((gk ^ (l31 & 7)) << 3)]);
            bf16x8_t k1 = *(const bf16x8_t*)(&KS[par][(32 + l31) * 64 + ((gk ^ (l31 & 7)) << 3)]);
            st[0] = __builtin_amdgcn_mfma_f32_32x32x16_bf16(k0, qf[s], st[0], 0, 0, 0);
            st[1] = __builtin_amdgcn_mfma_f32_32x32x16_bf16(k1, qf[s], st[1], 0, 0, 0);
        }

        float psum = 0.f;
#pragma unroll
        for (int t = 0; t < 2; ++t)
#pragma unroll
            for (int r = 0; r < 16; ++r) {
                float p = exp2f(st[t][r]);
                st[t][r] = p;
                psum += p;
            }
        psum += __shfl_xor(psum, 32);
        lrun += psum;

        bf16x8_t pf[4];
#pragma unroll
        for (int t = 0; t < 2; ++t) {
            unsigned wv[8], ov[8];
#pragma unroll
            for (int j = 0; j < 8; ++j) wv[j] = pk2(st[t][2 * j], st[t][2 * j + 1]);
#pragma unroll
            for (int j = 0; j < 8; ++j) ov[j] = (unsigned)__shfl_xor((int)wv[j], 32);
#pragma unroll
            for (int sh = 0; sh < 2; ++sh) {
                int b = sh * 4;
                union { unsigned u[4]; bf16x8_t v; } u8;
                u8.u[0] = hi ? ov[b + 2] : wv[b + 0];
                u8.u[1] = hi ? ov[b + 3] : wv[b + 1];
                u8.u[2] = hi ? wv[b + 2] : ov[b + 0];
                u8.u[3] = hi ? wv[b + 3] : ov[b + 1];
                pf[t * 2 + sh] = u8.v;
            }
        }

#pragma unroll
        for (int s = 0; s < 4; ++s) {
            int gk = s * 2 + hi;
            bf16x8_t v0 = *(const bf16x8_t*)(&VS[par][l31 * 64 + ((gk ^ (l31 & 7)) << 3)]);
            bf16x8_t v1 = *(const bf16x8_t*)(&VS[par][(32 + l31) * 64 + ((gk ^ (l31 & 7)) << 3)]);
            ot[0] = __builtin_amdgcn_mfma_f32_32x32x16_bf16(v0, pf[s], ot[0], 0, 0, 0);
            ot[1] = __builtin_amdgcn_mfma_f32_32x32x16_bf16(v1, pf[s], ot[1], 0, 0, 0);
        }
        FENCED_BARRIER();   // all reads done before next staging overwrites
    }

    // ---- cross-parity combine (KS = 4096-float O-red, VS head = l-red) ----
    float* redO = (float*)KS;            // exactly 4096 floats
    float* redL = (float*)VS;            // 128 floats
    if (par == 1) {
#pragma unroll
        for (int n = 0; n < 2; ++n)
#pragma unroll
            for (int r = 0; r < 16; ++r)
                redO[(qw * 32 + n * 16 + r) * 64 + lane] = ot[n][r];
        redL[qw * 64 + lane] = lrun;
    }
    FENCED_BARRIER();
    if (par == 1) return;
#pragma unroll
    for (int n = 0; n < 2; ++n)
#pragma unroll
        for (int r = 0; r < 16; ++r)
            ot[n][r] += redO[(qw * 32 + n * 16 + r) * 64 + lane];
    lrun += redL[qw * 64 + lane];

    // ---- epilogue (par-0 waves): private transpose region in VS ----
    float invl = 1.0f / lrun;
    ushort* Os = (ushort*)VS + 256 + qw * 2112;   // past redL, disjoint per qw
#pragma unroll
    for (int n = 0; n < 2; ++n)
#pragma unroll
        for (int r = 0; r < 16; ++r) {
            int d = n * 32 + (r & 3) + 8 * (r >> 2) + 4 * hi;
            Os[d * 33 + l31] = __bfloat16_as_ushort(__float2bfloat16(ot[n][r] * invl));
        }
    // within-wave LDS RAW: compiler inserts lgkmcnt; no cross-wave dep
    {
        unsigned ow2[16];
#pragma unroll
        for (int j = 0; j < 16; ++j) {
            unsigned lo = Os[(hi * 32 + 2 * j) * 33 + l31];
            unsigned hh = Os[(hi * 32 + 2 * j + 1) * 33 + l31];
            ow2[j] = lo | (hh << 16);
        }
        uint4* gd = (uint4*)(attnb + (size_t)(t0 + l31) * D_MODEL + h * DH + hi * 32);
        gd[0] = make_uint4(ow2[0], ow2[1], ow2[2], ow2[3]);
        gd[1] = make_uint4(ow2[4], ow2[5], ow2[6], ow2[7]);
        gd[2] = make_uint4(ow2[8], ow2[9], ow2[10], ow2[11]);
        gd[3] = make_uint4(ow2[12], ow2[13], ow2[14], ow2[15]);
    }
}

// ---------------------------------------------------------------------------
extern "C" void kernel_launch(void* const* d_in, const int* in_sizes, int n_in,
                              void* d_out, int out_size, void* d_ws, size_t ws_size,
                              hipStream_t stream) {
    const float* hidden = (const float*)d_in[0];
    const float* Wqkv   = (const float*)d_in[1];
    const float* Wo     = (const float*)d_in[2];
    const int*   pos    = (const int*)d_in[3];

    char* ws = (char*)d_ws;
    __hip_bfloat16* Xb    = (__hip_bfloat16*)(ws);              // 6,291,456
    __hip_bfloat16* Wqkvt = (__hip_bfloat16*)(ws + 6291456);    // 3,538,944
    __hip_bfloat16* Wot   = (__hip_bfloat16*)(ws + 9830400);    // 1,179,648
    __hip_bfloat16* Qb    = (__hip_bfloat16*)(ws + 11010048);   // 6,291,456
    __hip_bfloat16* Kb    = (__hip_bfloat16*)(ws + 17301504);   // 6,291,456
    __hip_bfloat16* Vtb   = (__hip_bfloat16*)(ws + 23592960);   // 6,291,456
    __hip_bfloat16* attnb = (__hip_bfloat16*)(ws + 29884416);   // 6,291,456
    float2* rtab          = (float2*)(ws + 36175872);           // 1,048,576
    float* out = (float*)d_out;

    prep_inputs<<<4160, 256, 0, stream>>>(hidden, Wqkv, Wo, pos, Xb, Wqkvt, Wot, rtab);

    gemm_qkv_fused<<<dim3(18, T_TOK / 64), 256, 0, stream>>>(
        Xb, Wqkvt, rtab, Qb, Kb, Vtb);

    attn_mfma<<<768, 256, 0, stream>>>(Qb, Kb, Vtb, attnb);

    gemm_wo64<<<dim3(D_MODEL / 64, T_TOK / 64), 256, 0, stream>>>(
        attnb, Wot, out);
}